// Round 12
// baseline (183.712 us; speedup 1.0000x reference)
//
#include <hip/hip_runtime.h>
#include <math.h>

#define NROWS 8192
#define DIN   60
#define DZ    16
#define NC    10

#define LOG2E 1.4426950408889634f

// K2 tiling: block = 256 thr (4 waves), each wave owns 32 rows (one 32x32
// i-tile). RB=128 rows/block, CJ=512 cols/chunk -> grid 64*16 = 1024 blocks.
#define RB      128
#define CJ      512
#define NRB     (NROWS / RB)     // 64 row blocks
#define NCH     (NROWS / CJ)     // 16 col chunks
#define WAVES   4

typedef short    bf16x8 __attribute__((ext_vector_type(8)));
typedef float    f32x4  __attribute__((ext_vector_type(4)));
typedef float    f32x16 __attribute__((ext_vector_type(16)));
typedef unsigned u32x2  __attribute__((ext_vector_type(2)));

__device__ __forceinline__ unsigned int bfr(float f) {
    // bf16 bits, round-half-up
    return (__float_as_uint(f) + 0x8000u) >> 16;
}

// ---------------------------------------------------------------------------
// K1 (fused): z = fc2(fc1(x)); zb[i][0..15] = bf16(z*sqrt(2*temp*log2e));
// bbf_i = log2e*(temp*||z||^2 - theta/2); xT = bf16 transpose of x augmented
// with a ones-column (row 60).
// ---------------------------------------------------------------------------
__global__ __launch_bounds__(64) void k1_all(
    const float* __restrict__ x,
    const float* __restrict__ w1, const float* __restrict__ b1,
    const float* __restrict__ w2, const float* __restrict__ b2,
    const float* __restrict__ temp_p, const float* __restrict__ theta_p,
    unsigned short* __restrict__ zb, float* __restrict__ bbf,
    unsigned short* __restrict__ xT)
{
    int i = blockIdx.x * 64 + threadIdx.x;

    float xr[DIN];
    const float4* xp = reinterpret_cast<const float4*>(x + (size_t)i * DIN);
    #pragma unroll
    for (int c = 0; c < 15; ++c) {
        float4 v = xp[c];
        xr[c*4+0] = v.x; xr[c*4+1] = v.y; xr[c*4+2] = v.z; xr[c*4+3] = v.w;
    }

    float n1[32];
    #pragma unroll
    for (int o = 0; o < 32; ++o) {
        float acc = b1[o];
        #pragma unroll
        for (int k = 0; k < DIN; ++k) acc = fmaf(w1[o*DIN+k], xr[k], acc);
        n1[o] = acc;
    }

    float z[DZ];
    float sq = 0.0f;
    #pragma unroll
    for (int u = 0; u < DZ; ++u) {
        float acc = b2[u];
        #pragma unroll
        for (int o = 0; o < 32; ++o) acc = fmaf(w2[u*32+o], n1[o], acc);
        z[u] = acc;
        sq = fmaf(acc, acc, sq);
    }

    float temp  = *temp_p;
    float theta = *theta_p;
    float s = sqrtf(2.0f * temp * LOG2E);

    unsigned int p[8];
    #pragma unroll
    for (int u = 0; u < 8; ++u) {
        unsigned int lo = bfr(z[2*u]   * s);
        unsigned int hi = bfr(z[2*u+1] * s);
        p[u] = lo | (hi << 16);
    }
    uint4* dst = reinterpret_cast<uint4*>(zb + (size_t)i * 16);
    dst[0] = make_uint4(p[0], p[1], p[2], p[3]);
    dst[1] = make_uint4(p[4], p[5], p[6], p[7]);

    bbf[i] = LOG2E * fmaf(temp, sq, -0.5f * theta);

    #pragma unroll
    for (int c = 0; c < DIN; ++c)
        xT[(size_t)c * NROWS + i] = (unsigned short)bfr(xr[c]);
    xT[(size_t)60 * NROWS + i] = 0x3F80;  // 1.0
    xT[(size_t)61 * NROWS + i] = 0;
    xT[(size_t)62 * NROWS + i] = 0;
    xT[(size_t)63 * NROWS + i] = 0;
}

// ---------------------------------------------------------------------------
// K2: 32x32x16 MFMA pairwise, LDS-free (r11-proven math), ATOMIC epilogue.
//   QK: S = mfma32(z_j, z_i); symmetric score matrix -> lane already owns its
//   PV A-row; lane<->lane+32 redistribution via 4x permlane32_swap (no LDS).
//   PV: H[i][n] += P @ xT-aug. Rowsum = col 60. Diag zeroed; k3 re-adds.
//   Epilogue: unsafeAtomicAdd (global_atomic_add_f32, fire-and-forget) into
//   hfin[8192][64] -- NO partials buffer, NO reduce kernel. The ledger r1-r11
//   shows the partials write->read->reduce pipeline costs ~90-100 us of graph
//   time regardless of layout; atomics into 2 MiB remove it structurally.
// ---------------------------------------------------------------------------
__global__ __launch_bounds__(256) void k2_mfma(
    const unsigned short* __restrict__ zb, const float* __restrict__ bbf,
    const unsigned short* __restrict__ xT, const float* __restrict__ theta_p,
    float* __restrict__ hfin)   // [NROWS][64] floats, pre-zeroed
{
    const int tid  = threadIdx.x;
    const int lane = tid & 63, wave = tid >> 6;
    const int ic = lane & 31;      // column within 32-tile (i for B, j for A)
    const int h  = lane >> 5;      // K-half selector
    const int rb = blockIdx.x & (NRB - 1);
    const int ch = blockIdx.x >> 6;          // NRB == 64
    const int it = rb * RB + wave * 32;
    const int j0 = ch * CJ;

    bf16x8 zbi = *reinterpret_cast<const bf16x8*>(zb + (size_t)(it + ic) * 16 + h * 8);
    const float bi = bbf[it + ic];
    const float nclamp = -(*theta_p) * LOG2E;

    // diagonal slot for this lane (used only when i-tile == j-tile)
    const int  dd   = ic - 4 * h;
    const bool dl   = (dd >= 0) && ((dd & 7) < 4);
    const int  dreg = dl ? (((dd >> 3) << 2) | (dd & 3)) : -1;

    f32x16 z16;
    #pragma unroll
    for (int k = 0; k < 16; ++k) z16[k] = 0.0f;
    f32x16 H0 = z16, H1 = z16;

    for (int jb = 0; jb < CJ / 32; ++jb) {
        const int jt = j0 + jb * 32;
        bf16x8 za = *reinterpret_cast<const bf16x8*>(zb + (size_t)(jt + ic) * 16 + h * 8);
        f32x16 S = __builtin_amdgcn_mfma_f32_32x32x16_bf16(za, zbi, z16, 0, 0, 0);

        const bool dblk = (it == jt);
        unsigned pk[8];
        #pragma unroll
        for (int u = 0; u < 4; ++u) {
            f32x4 bj = *reinterpret_cast<const f32x4*>(bbf + jt + u * 8 + 4 * h);
            unsigned ur[4];
            #pragma unroll
            for (int r = 0; r < 4; ++r) {
                const int reg = u * 4 + r;
                float n = (bi + bj[r]) - S[reg];
                n = fmaxf(n, nclamp);
                float P = __builtin_amdgcn_rcpf(1.0f + __builtin_amdgcn_exp2f(n));
                if (dblk && reg == dreg) P = 0.0f;   // diagonal
                ur[r] = __float_as_uint(P) + 0x8000u;
            }
            pk[u*2 + 0] = (ur[0] >> 16) | (ur[1] & 0xFFFF0000u);
            pk[u*2 + 1] = (ur[2] >> 16) | (ur[3] & 0xFFFF0000u);
        }

        // lane<->lane+32 redistribution: assemble PV A-frags in-register
        u32x2 sA = __builtin_amdgcn_permlane32_swap(pk[0], pk[2], false, false);
        u32x2 sB = __builtin_amdgcn_permlane32_swap(pk[1], pk[3], false, false);
        u32x2 sC = __builtin_amdgcn_permlane32_swap(pk[4], pk[6], false, false);
        u32x2 sD = __builtin_amdgcn_permlane32_swap(pk[5], pk[7], false, false);
        union { unsigned u[4]; bf16x8 v; } pa0, pa1;
        pa0.u[0] = sA[0]; pa0.u[1] = sB[0]; pa0.u[2] = sA[1]; pa0.u[3] = sB[1];
        pa1.u[0] = sC[0]; pa1.u[1] = sD[0]; pa1.u[2] = sC[1]; pa1.u[3] = sD[1];

        // PV: j in [jt,jt+16) via pa0, [jt+16,jt+32) via pa1
        {
            bf16x8 xb0 = *reinterpret_cast<const bf16x8*>(
                xT + (size_t)(ic) * NROWS + jt + h*8);
            bf16x8 xb1 = *reinterpret_cast<const bf16x8*>(
                xT + (size_t)(ic) * NROWS + jt + 16 + h*8);
            H0 = __builtin_amdgcn_mfma_f32_32x32x16_bf16(pa0.v, xb0, H0, 0, 0, 0);
            H0 = __builtin_amdgcn_mfma_f32_32x32x16_bf16(pa1.v, xb1, H0, 0, 0, 0);
        }
        {
            bf16x8 xb0 = *reinterpret_cast<const bf16x8*>(
                xT + (size_t)(32 + ic) * NROWS + jt + h*8);
            bf16x8 xb1 = *reinterpret_cast<const bf16x8*>(
                xT + (size_t)(32 + ic) * NROWS + jt + 16 + h*8);
            H1 = __builtin_amdgcn_mfma_f32_32x32x16_bf16(pa0.v, xb0, H1, 0, 0, 0);
            H1 = __builtin_amdgcn_mfma_f32_32x32x16_bf16(pa1.v, xb1, H1, 0, 0, 0);
        }
    }

    // epilogue: direct atomic accumulate into hfin[row][col]
    // H0: cols 0..31 (n=ic), H1: cols 32..63; row = it + (reg&3)+8*(reg>>2)+4*h
    #pragma unroll
    for (int reg = 0; reg < 16; ++reg) {
        const int row = it + (reg & 3) + 8 * (reg >> 2) + 4 * h;
        unsafeAtomicAdd(hfin + (size_t)row * 64 + ic,      H0[reg]);
        unsafeAtomicAdd(hfin + (size_t)row * 64 + 32 + ic, H1[reg]);
    }
}

// ---------------------------------------------------------------------------
// K3h: +x_i / +1 (exact diagonal), normalize, fc3, fc6, softmax
// ---------------------------------------------------------------------------
__global__ __launch_bounds__(64) void k3_head(
    const float* __restrict__ x,
    const float* __restrict__ w3, const float* __restrict__ b3,
    const float* __restrict__ w6, const float* __restrict__ b6,
    const float* __restrict__ hfin,
    float* __restrict__ out)
{
    int i = blockIdx.x * 64 + threadIdx.x;

    const float* hi = hfin + (size_t)i * 64;
    const float* xi = x + (size_t)i * DIN;

    float rd = __builtin_amdgcn_rcpf(hi[60] + 1.0f);

    float h[DIN];
    #pragma unroll
    for (int k = 0; k < DIN; ++k) h[k] = (hi[k] + xi[k]) * rd;

    float g[8];
    #pragma unroll
    for (int o = 0; o < 8; ++o) {
        float a = b3[o];
        #pragma unroll
        for (int k = 0; k < DIN; ++k) a = fmaf(w3[o*DIN+k], h[k], a);
        g[o] = a;
    }

    float l[NC];
    float m = -3.0e38f;
    #pragma unroll
    for (int c = 0; c < NC; ++c) {
        float a = b6[c];
        #pragma unroll
        for (int o = 0; o < 8; ++o) a = fmaf(w6[c*8+o], g[o], a);
        l[c] = a;
        m = fmaxf(m, a);
    }
    float e[NC];
    float sum = 0.0f;
    #pragma unroll
    for (int c = 0; c < NC; ++c) {
        e[c] = __builtin_amdgcn_exp2f((l[c] - m) * LOG2E);
        sum += e[c];
    }
    float rsum = __builtin_amdgcn_rcpf(sum);
    #pragma unroll
    for (int c = 0; c < NC; ++c) out[(size_t)i * NC + c] = e[c] * rsum;
}

// ---------------------------------------------------------------------------
extern "C" void kernel_launch(void* const* d_in, const int* in_sizes, int n_in,
                              void* d_out, int out_size, void* d_ws, size_t ws_size,
                              hipStream_t stream)
{
    const float* x     = (const float*)d_in[0];
    const float* w1    = (const float*)d_in[1];
    const float* b1    = (const float*)d_in[2];
    const float* w2    = (const float*)d_in[3];
    const float* b2    = (const float*)d_in[4];
    const float* w3    = (const float*)d_in[5];
    const float* b3    = (const float*)d_in[6];
    const float* w6    = (const float*)d_in[7];
    const float* b6    = (const float*)d_in[8];
    const float* temp  = (const float*)d_in[9];
    const float* theta = (const float*)d_in[10];
    float* out = (float*)d_out;

    // ws carve-up: 256K + 32K + 1M + 2MiB = ~3.3 MiB
    char* p = (char*)d_ws;
    unsigned short* zbuf = (unsigned short*)p;  p += (size_t)NROWS * 16 * 2;      // 256 KiB
    float*          bbf  = (float*)p;           p += (size_t)NROWS * 4;           // 32 KiB
    unsigned short* xT   = (unsigned short*)p;  p += (size_t)64 * NROWS * 2;      // 1 MiB
    float*          hfin = (float*)p;           // [NROWS][64] = 2 MiB

    hipMemsetAsync(hfin, 0, (size_t)NROWS * 64 * sizeof(float), stream);
    k1_all <<<NROWS / 64, 64, 0, stream>>>(x, w1, b1, w2, b2, temp, theta, zbuf, bbf, xT);
    k2_mfma<<<NRB * NCH, 256, 0, stream>>>(zbuf, bbf, xT, theta, hfin);
    k3_head<<<NROWS / 64, 64, 0, stream>>>(x, w3, b3, w6, b6, hfin, out);
}